// Round 3
// baseline (310.550 us; speedup 1.0000x reference)
//
#include <hip/hip_runtime.h>

#define NN 2048
#define EPS 0.01f
#define ROWS 8            // rows of W per block
#define BLOCKS_PER_B 256  // 2048 / 8
#define NBLK (8 * BLOCKS_PER_B)  // 2048 blocks

// Native clang vector type: __builtin_nontemporal_load requires a pointer
// to scalar/vector-of-scalar, not HIP_vector_type<float,4>.
typedef float f32x4 __attribute__((ext_vector_type(4)));

// Stage 1: 2048 blocks (256/batch), 256 threads.
//   - __launch_bounds__(256, 8): cap VGPR at 64 -> 8 waves/SIMD = 32
//     waves/CU (2x round-2's 16/CU). Theory: stage1 runs at ~1 TB/s
//     because 4 waves/SIMD can't keep enough HBM misses in flight;
//     wave-level concurrency, not per-wave burst depth, is what the
//     memory system can actually track.
//   - Hoist depth 8 (4 rows x 2 float4) = 32 data VGPRs, fits the cap.
//   - Row-anchor pred_i values forced to SGPRs via readfirstlane
//     (block-uniform addresses) to free VGPR budget.
//   - All W loads nontemporal (no L2 allocation; proven +16 us vs plain).
__global__ __launch_bounds__(256, 8) void coloring_loss_stage1(
    const float* __restrict__ W,
    const float* __restrict__ pred,
    float* __restrict__ partial)
{
    __shared__ float s_partial[4];  // 4 waves

    const int bid  = blockIdx.x;
    const int b    = bid >> 8;               // bid / 256
    const int row0 = (bid & 255) * ROWS;     // first row this block owns
    const int t    = threadIdx.x;

    const float* predb = pred + (size_t)b * NN;

    // This thread's 8 comparand pred_j values -> registers.
    const f32x4 pj0 = ((const f32x4*)predb)[t];
    const f32x4 pj1 = ((const f32x4*)predb)[t + 256];

    // Row-anchor pred_i values: block-uniform -> SGPRs (readfirstlane).
    float pis[ROWS];
#pragma unroll
    for (int r = 0; r < ROWS; ++r)
        pis[r] = __uint_as_float(
            __builtin_amdgcn_readfirstlane(__float_as_uint(predb[row0 + r])));

    // W[b, 1, row0, :] base.
    const float* wbase = W + (((size_t)b * 2 + 1) * (size_t)NN + (size_t)row0) * (size_t)NN;

    int cnt = 0;
#pragma unroll
    for (int half = 0; half < 2; ++half) {
        // Issue 8 nontemporal float4 loads (4 rows), then consume.
        f32x4 wa[4], wb[4];
#pragma unroll
        for (int r = 0; r < 4; ++r) {
            const f32x4* w4 =
                (const f32x4*)(wbase + (size_t)(half * 4 + r) * NN);
            wa[r] = __builtin_nontemporal_load(w4 + t);
            wb[r] = __builtin_nontemporal_load(w4 + t + 256);
        }
#pragma unroll
        for (int r = 0; r < 4; ++r) {
            const float pi = pis[half * 4 + r];
            const f32x4 a = wa[r];
            const f32x4 c = wb[r];
            cnt += (a.x == 1.0f) && (fabsf(pi - pj0.x) < EPS);
            cnt += (a.y == 1.0f) && (fabsf(pi - pj0.y) < EPS);
            cnt += (a.z == 1.0f) && (fabsf(pi - pj0.z) < EPS);
            cnt += (a.w == 1.0f) && (fabsf(pi - pj0.w) < EPS);
            cnt += (c.x == 1.0f) && (fabsf(pi - pj1.x) < EPS);
            cnt += (c.y == 1.0f) && (fabsf(pi - pj1.y) < EPS);
            cnt += (c.z == 1.0f) && (fabsf(pi - pj1.z) < EPS);
            cnt += (c.w == 1.0f) && (fabsf(pi - pj1.w) < EPS);
        }
    }

    // Wave (64-lane) shuffle reduction.
#pragma unroll
    for (int off = 32; off > 0; off >>= 1)
        cnt += __shfl_down(cnt, off, 64);

    const int wave = t >> 6;
    const int lane = t & 63;
    if (lane == 0) s_partial[wave] = (float)cnt;
    __syncthreads();

    if (t == 0) {
        partial[bid] = s_partial[0] + s_partial[1] + s_partial[2] + s_partial[3];
    }
}

// Stage 2: one block reduces the 2048 partials -> out[0]. Overwrites out
// unconditionally (d_out is poisoned 0xAA before every timed launch).
__global__ __launch_bounds__(256) void coloring_loss_stage2(
    const float* __restrict__ partial,
    float* __restrict__ out)
{
    __shared__ float s_partial[4];
    const int t = threadIdx.x;

    const f32x4* p4 = (const f32x4*)partial;  // 2048 floats = 512 float4
    const f32x4 a = p4[t];
    const f32x4 c = p4[t + 256];
    float s = a.x + a.y + a.z + a.w + c.x + c.y + c.z + c.w;

#pragma unroll
    for (int off = 32; off > 0; off >>= 1)
        s += __shfl_down(s, off, 64);

    const int wave = t >> 6;
    const int lane = t & 63;
    if (lane == 0) s_partial[wave] = s;
    __syncthreads();

    if (t == 0)
        out[0] = s_partial[0] + s_partial[1] + s_partial[2] + s_partial[3];
}

extern "C" void kernel_launch(void* const* d_in, const int* in_sizes, int n_in,
                              void* d_out, int out_size, void* d_ws, size_t ws_size,
                              hipStream_t stream) {
    const float* W    = (const float*)d_in[0];  // (8, 2, 2048, 2048) f32
    const float* pred = (const float*)d_in[1];  // (8, 2048) f32
    // d_in[2] (tgt) unused by the loss.
    float* out     = (float*)d_out;
    float* partial = (float*)d_ws;  // 2048 floats of scratch

    coloring_loss_stage1<<<NBLK, 256, 0, stream>>>(W, pred, partial);
    coloring_loss_stage2<<<1, 256, 0, stream>>>(partial, out);
}